// Round 1
// baseline (445.363 us; speedup 1.0000x reference)
//
#include <hip/hip_runtime.h>
#include <math.h>

#define L 512
#define NCH 21      // channels in x
#define H 30        // seq_hmm rows
#define NAA 20      // aa channels used (x[:,1:,:])
#define WSTRIDE 50  // W is [3, 20+H] = [3, 50]

typedef float v2f __attribute__((ext_vector_type(2)));

// proj[o*L + l] = sum_h W[o][20+h] * seq_hmm[h][l] + b[o]
// One-time precompute (R1-proven: cheaper than per-block recompute, R4 -6us).
__global__ void precompute_proj(const float* __restrict__ seq_hmm,
                                const float* __restrict__ W,
                                const float* __restrict__ bvec,
                                float* __restrict__ proj) {
    const int l = threadIdx.x;  // 512 threads, 1 block
    float a0 = bvec[0], a1 = bvec[1], a2 = bvec[2];
#pragma unroll
    for (int h = 0; h < H; ++h) {
        const float s = seq_hmm[h * L + l];
        a0 = fmaf(W[0 * WSTRIDE + NAA + h], s, a0);
        a1 = fmaf(W[1 * WSTRIDE + NAA + h], s, a1);
        a2 = fmaf(W[2 * WSTRIDE + NAA + h], s, a2);
    }
    proj[0 * L + l] = a0;
    proj[1 * L + l] = a1;
    proj[2 * L + l] = a2;
}

// One block per sample b; 256 threads; thread t owns columns 2t, 2t+1.
// R5 theory: 128thr/4col variant exceeded 64 VGPR -> 4 waves/SIMD occupancy
// cap -> HBM latency under-hidden (~70% of achievable BW). 2 cols/thread
// halves live state (a[3][2], m[2], xg[2], wss[3][2]); __launch_bounds__
// (256,8) pins VGPR<=64 -> 8 waves/SIMD.
// NOTE: precise expf/logf required -- __expf/__logf fail absmax (R2: 2.7e-2).
// NOTE: plain cached loads -- nontemporal bypassed L3, +4-10us (R3/R4).
__global__ __launch_bounds__(256, 8) void qpml_main(
        const float* __restrict__ x,       // [B,21,L]
        const float* __restrict__ ss_hmm,  // [3,L]
        const float* __restrict__ W,       // [3,50]
        const float* __restrict__ proj,    // [3,L]
        float* __restrict__ out) {         // [B]
    const int b = blockIdx.x;
    const int t = threadIdx.x;  // 0..255
    const float* xb = x + (size_t)b * NCH * L;

    // stage W[o][0..19] into LDS
    __shared__ float sW[3][NAA];
    if (t < 3 * NAA) ((float*)sW)[t] = W[(t / NAA) * WSTRIDE + (t % NAA)];
    __syncthreads();

    const int l0 = 2 * t;

    // channel 0 (gap channel) values
    float xg[2];
    {
        const v2f v = *(const v2f*)(xb + l0);
        xg[0] = v[0]; xg[1] = v[1];
    }

    float m[2] = {-INFINITY, -INFINITY};
    float a[3][2];
#pragma unroll
    for (int o = 0; o < 3; ++o) {
        const v2f p = *(const v2f*)(proj + o * L + l0);
        a[o][0] = p[0]; a[o][1] = p[1];
    }

#pragma unroll
    for (int c = 1; c < NCH; ++c) {
        const v2f v = *(const v2f*)(xb + c * L + l0);
        const float w0 = sW[0][c - 1];
        const float w1 = sW[1][c - 1];
        const float w2 = sW[2][c - 1];
#pragma unroll
        for (int j = 0; j < 2; ++j) {
            m[j] = fmaxf(m[j], v[j]);
            a[0][j] = fmaf(w0, v[j], a[0][j]);
            a[1][j] = fmaf(w1, v[j], a[1][j]);
            a[2][j] = fmaf(w2, v[j], a[2][j]);
        }
    }

    float wss[3][2];
#pragma unroll
    for (int o = 0; o < 3; ++o) {
        const v2f s = *(const v2f*)(ss_hmm + o * L + l0);
        wss[o][0] = s[0]; wss[o][1] = s[1];
    }

    float lsum = 0.0f, lcnt = 0.0f;
#pragma unroll
    for (int j = 0; j < 2; ++j) {
        if (m[j] > xg[j]) {  // argmax != 0 (first-occurrence tie -> gap)
            const float mm = fmaxf(a[0][j], fmaxf(a[1][j], a[2][j]));
            const float e0 = expf(a[0][j] - mm);
            const float e1 = expf(a[1][j] - mm);
            const float e2 = expf(a[2][j] - mm);
            const float inv = 1.0f / (e0 + e1 + e2);
            lsum = fmaf(wss[0][j] * e0 + wss[1][j] * e1 + wss[2][j] * e2, inv, lsum);
            lcnt += 1.0f;
        }
    }

    // 64-lane wave shuffle reduction
#pragma unroll
    for (int off = 32; off >= 1; off >>= 1) {
        lsum += __shfl_down(lsum, off);
        lcnt += __shfl_down(lcnt, off);
    }

    __shared__ float s_s[4], s_c[4];
    if ((t & 63) == 0) { s_s[t >> 6] = lsum; s_c[t >> 6] = lcnt; }
    __syncthreads();
    if (t == 0) {
        out[b] = logf((s_s[0] + s_s[1] + s_s[2] + s_s[3]) /
                      (s_c[0] + s_c[1] + s_c[2] + s_c[3]));
    }
}

extern "C" void kernel_launch(void* const* d_in, const int* in_sizes, int n_in,
                              void* d_out, int out_size, void* d_ws, size_t ws_size,
                              hipStream_t stream) {
    const float* x       = (const float*)d_in[0];  // [4096,21,512]
    const float* seq_hmm = (const float*)d_in[1];  // [30,512]
    const float* ss_hmm  = (const float*)d_in[2];  // [3,512]
    const float* W       = (const float*)d_in[3];  // [3,50]
    const float* bvec    = (const float*)d_in[4];  // [3]
    float* out = (float*)d_out;                    // [4096]
    float* proj = (float*)d_ws;                    // 3*512 floats = 6 KB

    precompute_proj<<<1, L, 0, stream>>>(seq_hmm, W, bvec, proj);

    const int B = in_sizes[0] / (NCH * L);  // 4096
    qpml_main<<<B, 256, 0, stream>>>(x, ss_hmm, W, proj, out);
}

// Round 2
// 251.118 us; speedup vs baseline: 1.7735x; 1.7735x over previous
//
#include <hip/hip_runtime.h>
#include <math.h>

#define L 512
#define NCH 21      // channels in x
#define H 30        // seq_hmm rows
#define NAA 20      // aa channels used (x[:,1:,:])
#define WSTRIDE 50  // W is [3, 20+H] = [3, 50]

typedef float v4f __attribute__((ext_vector_type(4)));

// proj[o*L + l] = sum_h W[o][20+h] * seq_hmm[h][l] + b[o]
// One-time precompute (R1-proven: cheaper than per-block recompute, R4 -6us).
__global__ void precompute_proj(const float* __restrict__ seq_hmm,
                                const float* __restrict__ W,
                                const float* __restrict__ bvec,
                                float* __restrict__ proj) {
    const int l = threadIdx.x;  // 512 threads, 1 block
    float a0 = bvec[0], a1 = bvec[1], a2 = bvec[2];
#pragma unroll
    for (int h = 0; h < H; ++h) {
        const float s = seq_hmm[h * L + l];
        a0 = fmaf(W[0 * WSTRIDE + NAA + h], s, a0);
        a1 = fmaf(W[1 * WSTRIDE + NAA + h], s, a1);
        a2 = fmaf(W[2 * WSTRIDE + NAA + h], s, a2);
    }
    proj[0 * L + l] = a0;
    proj[1 * L + l] = a1;
    proj[2 * L + l] = a2;
}

// 128 threads/block; thread t owns columns 4t..4t+3 (16B/lane loads).
// Grid-stride over samples, grid=2048 -> 2 samples/block back-to-back so
// next sample's loads overlap current sample's epilogue.
// R5 POST-MORTEM: __launch_bounds__(256,8) forced VGPR=32 -> load ILP
// destroyed -> 3.2 TB/s, 270us (5.5x regression). This kernel is
// load-ILP-bound, NOT occupancy-bound. Do NOT clamp VGPRs.
// NOTE: precise expf/logf required -- __expf/__logf fail absmax (R2: 2.7e-2).
// NOTE: plain cached loads -- nontemporal bypassed L3, +4-10us (R3/R4).
__global__ __launch_bounds__(128) void qpml_main(
        const float* __restrict__ x,       // [B,21,L]
        const float* __restrict__ ss_hmm,  // [3,L]
        const float* __restrict__ W,       // [3,50]
        const float* __restrict__ proj,    // [3,L]
        float* __restrict__ out,           // [B]
        int B) {
    const int t = threadIdx.x;  // 0..127

    // stage W[o][0..19] into LDS
    __shared__ float sW[3][NAA];
    if (t < 3 * NAA) ((float*)sW)[t] = W[(t / NAA) * WSTRIDE + (t % NAA)];
    __syncthreads();

    const int l0 = 4 * t;

    // Sample-invariant per-thread state, register-cached ONCE:
    // softmax-input init (proj) and ss weights. 24 VGPRs, removes 6 of 27
    // loads per sample.
    float pin[3][4], wss[3][4];
#pragma unroll
    for (int o = 0; o < 3; ++o) {
        const v4f p = *(const v4f*)(proj + o * L + l0);
        pin[o][0] = p[0]; pin[o][1] = p[1]; pin[o][2] = p[2]; pin[o][3] = p[3];
        const v4f s = *(const v4f*)(ss_hmm + o * L + l0);
        wss[o][0] = s[0]; wss[o][1] = s[1]; wss[o][2] = s[2]; wss[o][3] = s[3];
    }

    __shared__ float s_s[2], s_c[2];

    for (int b = blockIdx.x; b < B; b += gridDim.x) {
        const float* xb = x + (size_t)b * NCH * L;

        // channel 0 (gap channel) values
        float xg[4];
        {
            const v4f v = *(const v4f*)(xb + l0);
            xg[0] = v[0]; xg[1] = v[1]; xg[2] = v[2]; xg[3] = v[3];
        }

        float m[4] = {-INFINITY, -INFINITY, -INFINITY, -INFINITY};
        float a[3][4];
#pragma unroll
        for (int o = 0; o < 3; ++o)
#pragma unroll
            for (int j = 0; j < 4; ++j) a[o][j] = pin[o][j];

#pragma unroll
        for (int c = 1; c < NCH; ++c) {
            const v4f v = *(const v4f*)(xb + c * L + l0);
            const float w0 = sW[0][c - 1];
            const float w1 = sW[1][c - 1];
            const float w2 = sW[2][c - 1];
#pragma unroll
            for (int j = 0; j < 4; ++j) {
                m[j] = fmaxf(m[j], v[j]);
                a[0][j] = fmaf(w0, v[j], a[0][j]);
                a[1][j] = fmaf(w1, v[j], a[1][j]);
                a[2][j] = fmaf(w2, v[j], a[2][j]);
            }
        }

        float lsum = 0.0f, lcnt = 0.0f;
#pragma unroll
        for (int j = 0; j < 4; ++j) {
            if (m[j] > xg[j]) {  // argmax != 0 (first-occurrence tie -> gap)
                const float mm = fmaxf(a[0][j], fmaxf(a[1][j], a[2][j]));
                const float e0 = expf(a[0][j] - mm);
                const float e1 = expf(a[1][j] - mm);
                const float e2 = expf(a[2][j] - mm);
                const float inv = 1.0f / (e0 + e1 + e2);
                lsum = fmaf(wss[0][j] * e0 + wss[1][j] * e1 + wss[2][j] * e2,
                            inv, lsum);
                lcnt += 1.0f;
            }
        }

        // 64-lane wave shuffle reduction
#pragma unroll
        for (int off = 32; off >= 1; off >>= 1) {
            lsum += __shfl_down(lsum, off);
            lcnt += __shfl_down(lcnt, off);
        }

        if ((t & 63) == 0) { s_s[t >> 6] = lsum; s_c[t >> 6] = lcnt; }
        __syncthreads();
        if (t == 0) {
            out[b] = logf((s_s[0] + s_s[1]) / (s_c[0] + s_c[1]));
        }
        __syncthreads();  // protect s_s/s_c reuse next iteration
    }
}

extern "C" void kernel_launch(void* const* d_in, const int* in_sizes, int n_in,
                              void* d_out, int out_size, void* d_ws, size_t ws_size,
                              hipStream_t stream) {
    const float* x       = (const float*)d_in[0];  // [4096,21,512]
    const float* seq_hmm = (const float*)d_in[1];  // [30,512]
    const float* ss_hmm  = (const float*)d_in[2];  // [3,512]
    const float* W       = (const float*)d_in[3];  // [3,50]
    const float* bvec    = (const float*)d_in[4];  // [3]
    float* out = (float*)d_out;                    // [4096]
    float* proj = (float*)d_ws;                    // 3*512 floats = 6 KB

    precompute_proj<<<1, L, 0, stream>>>(seq_hmm, W, bvec, proj);

    const int B = in_sizes[0] / (NCH * L);  // 4096
    const int grid = (B < 2048) ? B : 2048;
    qpml_main<<<grid, 128, 0, stream>>>(x, ss_hmm, W, proj, out, B);
}